// Round 5
// baseline (41.125 us; speedup 1.0000x reference)
//
#include <hip/hip_runtime.h>
#include <hip/hip_bf16.h>

// out[b,o,n] = sum_{c<512} Wf[o,c] * features[b,c,n]  (attention term ~1e-6, omitted)
// B=8, C=512, N=4096, Wf is (512,1024) row-major; only first 512 cols used.
//
// 256x128 tile, BK=32, 512 threads (8 waves, 4x2 -> 64x64 wave tiles), 2 blk/CU.
// Double-buffered bf16 LDS with granule-XOR swizzle (conflict-free b128 R+W),
// ONE barrier per K-step: staging(it+1, buf^1) overlaps MFMA(it, buf).

#define BATCH 8
#define CIN   512
#define NPIX  4096
#define WF_LD 1024

#define BM 256
#define BN 128
#define BK 32   // 32 ushorts/row = 64B = 4 granules of 16B, no pad

typedef __attribute__((ext_vector_type(8))) short short8;
typedef __attribute__((ext_vector_type(4))) float f32x4;

static __device__ __forceinline__ unsigned pk2(float a, float b) {
    unsigned r;
    asm("v_cvt_pk_bf16_f32 %0, %1, %2" : "=v"(r) : "v"(a), "v"(b));
    return r;   // lo = bf16(a), hi = bf16(b)
}

union S8U { short8 s; unsigned u[4]; };

// ushort offset of 16B-granule g of row `row` (stride 32 ushorts, XOR swizzle)
static __device__ __forceinline__ int swz_off(int row, int g) {
    return row * 32 + ((g ^ ((row >> 1) & 3)) << 3);
}

__global__ __launch_bounds__(512, 4)
void AGCR_out_gemm(const float* __restrict__ features,
                   const float* __restrict__ Wf,
                   float* __restrict__ out)
{
    // batch -> XCD pin (512 = 8*64, bijective)
    const int fbid = blockIdx.x;
    const int b    = fbid & 7;
    const int idx  = fbid >> 3;        // 0..63
    const int bm   = (idx & 1) * BM;   // 2 channel tiles
    const int bn   = (idx >> 1) * BN;  // 32 pixel tiles

    const float* Fb = features + (size_t)b * CIN * NPIX;
    float*       Ob = out      + (size_t)b * CIN * NPIX;

    __shared__ __align__(16) ushort lA[2][BM * BK];  // Wf tiles, swizzled
    __shared__ __align__(16) ushort lB[2][BN * BK];  // features tiles, swizzled

    const int t    = threadIdx.x;
    const int lane = t & 63;
    const int w    = t >> 6;          // 0..7
    const int wm   = (w >> 1) * 64;   // 4 m-groups
    const int wn   = (w & 1) * 64;    // 2 n-groups

    // staging assignments
    const int am  = t >> 1;           // 0..255 : A row
    const int ag0 = (t & 1) * 2;      // A granules ag0, ag0+1  (k = ag0*8 ..)
    const int bnl = t & 127;          // 0..127 : B column (pixel)
    const int bg  = t >> 7;           // 0..3   : B granule (k-octet bg*8)

    const int rA = lane & 15;
    const int kq = lane >> 4;         // granule 0..3 (k = kq*8)

    f32x4 acc[4][4];
    #pragma unroll
    for (int i = 0; i < 4; ++i)
        #pragma unroll
        for (int j = 0; j < 4; ++j)
            acc[i][j] = (f32x4)0.f;

    const float* aPtr = Wf + (size_t)(bm + am) * WF_LD + ag0 * 8;  // + k0
    const float* bPtr = Fb + bn + bnl;                             // + k*NPIX

    // precomputed swizzled store offsets (row-dependent part is constant/thread)
    const int offA0 = swz_off(am, ag0);
    const int offA1 = swz_off(am, ag0 + 1);
    const int offB  = swz_off(bnl, bg);

    f32x4 Apf[4];
    float Bpf[8];

    // ---------------- prologue ----------------
    #pragma unroll
    for (int j = 0; j < 4; ++j) Apf[j] = *(const f32x4*)(aPtr + j * 4);
    #pragma unroll
    for (int i = 0; i < 8; ++i) Bpf[i] = bPtr[(size_t)(bg * 8 + i) * NPIX];

    {   // convert + write tile 0 -> buf 0
        S8U s0, s1;
        s0.u[0] = pk2(Apf[0][0], Apf[0][1]);
        s0.u[1] = pk2(Apf[0][2], Apf[0][3]);
        s0.u[2] = pk2(Apf[1][0], Apf[1][1]);
        s0.u[3] = pk2(Apf[1][2], Apf[1][3]);
        s1.u[0] = pk2(Apf[2][0], Apf[2][1]);
        s1.u[1] = pk2(Apf[2][2], Apf[2][3]);
        s1.u[2] = pk2(Apf[3][0], Apf[3][1]);
        s1.u[3] = pk2(Apf[3][2], Apf[3][3]);
        *(short8*)(&lA[0][offA0]) = s0.s;
        *(short8*)(&lA[0][offA1]) = s1.s;
        S8U sb;
        sb.u[0] = pk2(Bpf[0], Bpf[1]);
        sb.u[1] = pk2(Bpf[2], Bpf[3]);
        sb.u[2] = pk2(Bpf[4], Bpf[5]);
        sb.u[3] = pk2(Bpf[6], Bpf[7]);
        *(short8*)(&lB[0][offB]) = sb.s;
    }
    // issue tile-1 loads
    #pragma unroll
    for (int j = 0; j < 4; ++j) Apf[j] = *(const f32x4*)(aPtr + BK + j * 4);
    #pragma unroll
    for (int i = 0; i < 8; ++i) Bpf[i] = bPtr[(size_t)(BK + bg * 8 + i) * NPIX];
    __syncthreads();

    // ---------------- K loop: one barrier per iteration ----------------
    for (int it = 0; it < 16; ++it) {
        const int cur = it & 1;
        const ushort* pA = lA[cur];
        const ushort* pB = lB[cur];

        // stage tile it+1 into buf^1 (waits vmcnt; overlaps MFMA below)
        if (it < 15) {
            ushort* qA = lA[cur ^ 1];
            ushort* qB = lB[cur ^ 1];
            S8U s0, s1;
            s0.u[0] = pk2(Apf[0][0], Apf[0][1]);
            s0.u[1] = pk2(Apf[0][2], Apf[0][3]);
            s0.u[2] = pk2(Apf[1][0], Apf[1][1]);
            s0.u[3] = pk2(Apf[1][2], Apf[1][3]);
            s1.u[0] = pk2(Apf[2][0], Apf[2][1]);
            s1.u[1] = pk2(Apf[2][2], Apf[2][3]);
            s1.u[2] = pk2(Apf[3][0], Apf[3][1]);
            s1.u[3] = pk2(Apf[3][2], Apf[3][3]);
            *(short8*)(&qA[offA0]) = s0.s;
            *(short8*)(&qA[offA1]) = s1.s;
            S8U sb;
            sb.u[0] = pk2(Bpf[0], Bpf[1]);
            sb.u[1] = pk2(Bpf[2], Bpf[3]);
            sb.u[2] = pk2(Bpf[4], Bpf[5]);
            sb.u[3] = pk2(Bpf[6], Bpf[7]);
            *(short8*)(&qB[offB]) = sb.s;

            // issue tile it+2 loads
            if (it < 14) {
                const int k2 = (it + 2) * BK;
                #pragma unroll
                for (int j = 0; j < 4; ++j)
                    Apf[j] = *(const f32x4*)(aPtr + k2 + j * 4);
                #pragma unroll
                for (int i = 0; i < 8; ++i)
                    Bpf[i] = bPtr[(size_t)(k2 + bg * 8 + i) * NPIX];
            }
        }

        // MFMA on tile it from buf[cur]
        {
            short8 af[4], bf[4];
            #pragma unroll
            for (int mi = 0; mi < 4; ++mi)
                af[mi] = *(const short8*)(&pA[swz_off(wm + mi * 16 + rA, kq)]);
            #pragma unroll
            for (int ni = 0; ni < 4; ++ni)
                bf[ni] = *(const short8*)(&pB[swz_off(wn + ni * 16 + rA, kq)]);
            __builtin_amdgcn_s_setprio(1);
            #pragma unroll
            for (int mi = 0; mi < 4; ++mi)
                #pragma unroll
                for (int ni = 0; ni < 4; ++ni)
                    acc[mi][ni] = __builtin_amdgcn_mfma_f32_16x16x32_bf16(
                        af[mi], bf[ni], acc[mi][ni], 0, 0, 0);
            __builtin_amdgcn_s_setprio(0);
        }
        __syncthreads();
    }

    // ---------------- epilogue: D col=lane&15, row=(lane>>4)*4+r ----------------
    const int r0 = (lane >> 4) * 4;
    const int c0 = lane & 15;
    #pragma unroll
    for (int mi = 0; mi < 4; ++mi) {
        #pragma unroll
        for (int ni = 0; ni < 4; ++ni) {
            #pragma unroll
            for (int r = 0; r < 4; ++r) {
                const int row = bm + wm + mi * 16 + r0 + r;
                const int col = bn + wn + ni * 16 + c0;
                Ob[(size_t)row * NPIX + col] = acc[mi][ni][r];
            }
        }
    }
}

extern "C" void kernel_launch(void* const* d_in, const int* in_sizes, int n_in,
                              void* d_out, int out_size, void* d_ws, size_t ws_size,
                              hipStream_t stream) {
    const float* features = (const float*)d_in[0];
    const float* Wf       = (const float*)d_in[5];
    float*       out      = (float*)d_out;

    dim3 grid(CIN / BM * NPIX / BN * BATCH);  // 2*32*8 = 512 blocks, 2 per CU
    dim3 block(512);
    AGCR_out_gemm<<<grid, block, 0, stream>>>(features, Wf, out);
}

// Round 6
// 40.197 us; speedup vs baseline: 1.0231x; 1.0231x over previous
//
#include <hip/hip_runtime.h>
#include <hip/hip_bf16.h>

// out[b,o,n] = sum_{c<512} Wf[o,c] * features[b,c,n]  (attention term ~1e-6, omitted)
// B=8, C=512, N=4096, Wf is (512,1024) row-major; only first 512 cols used.
//
// 256x128 tile, BK=32, 512 threads (8 waves, 4x2 -> 64x64 wave tiles), 2 blk/CU.
// Double-buffered swizzled LDS, ONE barrier per K-step, MFMA-FIRST phase order:
//   ds_read+MFMA(it, buf) -> cvt+write(it+1, buf^1) -> issue loads(it+2) -> bar

#define BATCH 8
#define CIN   512
#define NPIX  4096
#define WF_LD 1024

#define BM 256
#define BN 128
#define BK 32   // 32 ushorts/row = 64B = 4 granules of 16B, no pad

typedef __attribute__((ext_vector_type(8))) short short8;
typedef __attribute__((ext_vector_type(4))) float f32x4;

static __device__ __forceinline__ unsigned pk2(float a, float b) {
    unsigned r;
    asm("v_cvt_pk_bf16_f32 %0, %1, %2" : "=v"(r) : "v"(a), "v"(b));
    return r;   // lo = bf16(a), hi = bf16(b)
}

union S8U { short8 s; unsigned u[4]; };

// ushort offset of 16B-granule g of row `row` (stride 32 ushorts, XOR swizzle)
static __device__ __forceinline__ int swz_off(int row, int g) {
    return row * 32 + ((g ^ ((row >> 1) & 3)) << 3);
}

__global__ __launch_bounds__(512, 4)
void AGCR_out_gemm(const float* __restrict__ features,
                   const float* __restrict__ Wf,
                   float* __restrict__ out)
{
    // batch -> XCD pin (512 = 8*64, bijective)
    const int fbid = blockIdx.x;
    const int b    = fbid & 7;
    const int idx  = fbid >> 3;        // 0..63
    const int bm   = (idx & 1) * BM;   // 2 channel tiles
    const int bn   = (idx >> 1) * BN;  // 32 pixel tiles

    const float* Fb = features + (size_t)b * CIN * NPIX;
    float*       Ob = out      + (size_t)b * CIN * NPIX;

    __shared__ __align__(16) ushort lA[2][BM * BK];  // Wf tiles, swizzled
    __shared__ __align__(16) ushort lB[2][BN * BK];  // features tiles, swizzled

    const int t    = threadIdx.x;
    const int lane = t & 63;
    const int w    = t >> 6;          // 0..7
    const int wm   = (w >> 1) * 64;   // 4 m-groups
    const int wn   = (w & 1) * 64;    // 2 n-groups

    // staging assignments
    const int am  = t >> 1;           // 0..255 : A row
    const int ag0 = (t & 1) * 2;      // A granules ag0, ag0+1
    const int bnl = t & 127;          // 0..127 : B column (pixel)
    const int bg  = t >> 7;           // 0..3   : B granule (k-octet bg*8)

    const int rA = lane & 15;
    const int kq = lane >> 4;         // granule 0..3 (k = kq*8)

    f32x4 acc[4][4];
    #pragma unroll
    for (int i = 0; i < 4; ++i)
        #pragma unroll
        for (int j = 0; j < 4; ++j)
            acc[i][j] = (f32x4)0.f;

    const float* aPtr = Wf + (size_t)(bm + am) * WF_LD + ag0 * 8;  // + k0
    const float* bPtr = Fb + bn + bnl;                             // + k*NPIX

    const int offA0 = swz_off(am, ag0);
    const int offA1 = swz_off(am, ag0 + 1);
    const int offB  = swz_off(bnl, bg);

    f32x4 Apf[4];
    float Bpf[8];

    // ---------------- prologue: tile 0 -> buf0, issue tile-1 loads ----------------
    #pragma unroll
    for (int j = 0; j < 4; ++j) Apf[j] = *(const f32x4*)(aPtr + j * 4);
    #pragma unroll
    for (int i = 0; i < 8; ++i) Bpf[i] = bPtr[(size_t)(bg * 8 + i) * NPIX];
    {
        S8U s0, s1;
        s0.u[0] = pk2(Apf[0][0], Apf[0][1]);
        s0.u[1] = pk2(Apf[0][2], Apf[0][3]);
        s0.u[2] = pk2(Apf[1][0], Apf[1][1]);
        s0.u[3] = pk2(Apf[1][2], Apf[1][3]);
        s1.u[0] = pk2(Apf[2][0], Apf[2][1]);
        s1.u[1] = pk2(Apf[2][2], Apf[2][3]);
        s1.u[2] = pk2(Apf[3][0], Apf[3][1]);
        s1.u[3] = pk2(Apf[3][2], Apf[3][3]);
        *(short8*)(&lA[0][offA0]) = s0.s;
        *(short8*)(&lA[0][offA1]) = s1.s;
        S8U sb;
        sb.u[0] = pk2(Bpf[0], Bpf[1]);
        sb.u[1] = pk2(Bpf[2], Bpf[3]);
        sb.u[2] = pk2(Bpf[4], Bpf[5]);
        sb.u[3] = pk2(Bpf[6], Bpf[7]);
        *(short8*)(&lB[0][offB]) = sb.s;
    }
    #pragma unroll
    for (int j = 0; j < 4; ++j) Apf[j] = *(const f32x4*)(aPtr + BK + j * 4);
    #pragma unroll
    for (int i = 0; i < 8; ++i) Bpf[i] = bPtr[(size_t)(BK + bg * 8 + i) * NPIX];
    __syncthreads();

    // ---------------- K loop: MFMA first, then stage; one barrier ----------------
    for (int it = 0; it < 16; ++it) {
        const int cur = it & 1;
        const ushort* pA = lA[cur];
        const ushort* pB = lB[cur];

        // phase 1: fragments + MFMA on tile it (no vmem dependence)
        {
            short8 af[4], bf[4];
            #pragma unroll
            for (int mi = 0; mi < 4; ++mi)
                af[mi] = *(const short8*)(&pA[swz_off(wm + mi * 16 + rA, kq)]);
            #pragma unroll
            for (int ni = 0; ni < 4; ++ni)
                bf[ni] = *(const short8*)(&pB[swz_off(wn + ni * 16 + rA, kq)]);
            __builtin_amdgcn_s_setprio(1);
            #pragma unroll
            for (int mi = 0; mi < 4; ++mi)
                #pragma unroll
                for (int ni = 0; ni < 4; ++ni)
                    acc[mi][ni] = __builtin_amdgcn_mfma_f32_16x16x32_bf16(
                        af[mi], bf[ni], acc[mi][ni], 0, 0, 0);
            __builtin_amdgcn_s_setprio(0);
        }

        // phase 2: stage tile it+1 into buf^1 (vmcnt wait lands AFTER the MFMAs)
        if (it < 15) {
            ushort* qA = lA[cur ^ 1];
            ushort* qB = lB[cur ^ 1];
            S8U s0, s1;
            s0.u[0] = pk2(Apf[0][0], Apf[0][1]);
            s0.u[1] = pk2(Apf[0][2], Apf[0][3]);
            s0.u[2] = pk2(Apf[1][0], Apf[1][1]);
            s0.u[3] = pk2(Apf[1][2], Apf[1][3]);
            s1.u[0] = pk2(Apf[2][0], Apf[2][1]);
            s1.u[1] = pk2(Apf[2][2], Apf[2][3]);
            s1.u[2] = pk2(Apf[3][0], Apf[3][1]);
            s1.u[3] = pk2(Apf[3][2], Apf[3][3]);
            *(short8*)(&qA[offA0]) = s0.s;
            *(short8*)(&qA[offA1]) = s1.s;
            S8U sb;
            sb.u[0] = pk2(Bpf[0], Bpf[1]);
            sb.u[1] = pk2(Bpf[2], Bpf[3]);
            sb.u[2] = pk2(Bpf[4], Bpf[5]);
            sb.u[3] = pk2(Bpf[6], Bpf[7]);
            *(short8*)(&qB[offB]) = sb.s;

            // phase 3: refill prefetch regs for tile it+2
            if (it < 14) {
                const int k2 = (it + 2) * BK;
                #pragma unroll
                for (int j = 0; j < 4; ++j)
                    Apf[j] = *(const f32x4*)(aPtr + k2 + j * 4);
                #pragma unroll
                for (int i = 0; i < 8; ++i)
                    Bpf[i] = bPtr[(size_t)(k2 + bg * 8 + i) * NPIX];
            }
        }
        __syncthreads();
    }

    // ---------------- epilogue: D col=lane&15, row=(lane>>4)*4+r ----------------
    const int r0 = (lane >> 4) * 4;
    const int c0 = lane & 15;
    #pragma unroll
    for (int mi = 0; mi < 4; ++mi) {
        #pragma unroll
        for (int ni = 0; ni < 4; ++ni) {
            #pragma unroll
            for (int r = 0; r < 4; ++r) {
                const int row = bm + wm + mi * 16 + r0 + r;
                const int col = bn + wn + ni * 16 + c0;
                Ob[(size_t)row * NPIX + col] = acc[mi][ni][r];
            }
        }
    }
}

extern "C" void kernel_launch(void* const* d_in, const int* in_sizes, int n_in,
                              void* d_out, int out_size, void* d_ws, size_t ws_size,
                              hipStream_t stream) {
    const float* features = (const float*)d_in[0];
    const float* Wf       = (const float*)d_in[5];
    float*       out      = (float*)d_out;

    dim3 grid(CIN / BM * NPIX / BN * BATCH);  // 2*32*8 = 512 blocks, 2 per CU
    dim3 block(512);
    AGCR_out_gemm<<<grid, block, 0, stream>>>(features, Wf, out);
}